// Round 2
// baseline (410.213 us; speedup 1.0000x reference)
//
#include <hip/hip_runtime.h>
#include <math.h>

#define N_NODES 50000
#define N_EDGES 800000
#define IN_CH 256
#define OUT_CH 64
#define NEG_SLOPE 0.2f

// ---------------------------------------------------------------------------
// Kernel A: feature = x @ W^T + b  (M=50000, K=256, N=64)
// Fused epilogue: e0[n], e1[n] (att partials), denom[n] = exp(lrelu(e0+e1))
// (the self-loop softmax term). Also zero-initializes deg[] for this block's
// rows (workspace is poisoned before every call).
// ---------------------------------------------------------------------------
__global__ __launch_bounds__(256) void k_gemm(
    const float* __restrict__ x, const float* __restrict__ W,
    const float* __restrict__ bias, const float* __restrict__ att,
    float* __restrict__ feature, float* __restrict__ e0,
    float* __restrict__ e1, float* __restrict__ denom,
    int* __restrict__ deg)
{
    constexpr int LDP = 68;
    __shared__ float xst[64][LDP];          // [k][row]
    __shared__ float wt[64][LDP];           // [k][col]

    const int t  = threadIdx.x;
    const int tx = t & 15;
    const int ty = t >> 4;
    const int row0 = blockIdx.x * 64;

    if (t < 64 && row0 + t < N_NODES) deg[row0 + t] = 0;

    float acc[4][4] = {};

    for (int kc = 0; kc < IN_CH; kc += 64) {
        __syncthreads();
        #pragma unroll
        for (int i = 0; i < 4; ++i) {
            int quad = t + i * 256;
            int r    = quad >> 4;
            int kq   = quad & 15;
            float4 v = make_float4(0.f, 0.f, 0.f, 0.f);
            int gr = row0 + r;
            if (gr < N_NODES)
                v = *reinterpret_cast<const float4*>(&x[gr * IN_CH + kc + kq * 4]);
            xst[kq * 4 + 0][r] = v.x;
            xst[kq * 4 + 1][r] = v.y;
            xst[kq * 4 + 2][r] = v.z;
            xst[kq * 4 + 3][r] = v.w;
            float4 w4 = *reinterpret_cast<const float4*>(&W[r * IN_CH + kc + kq * 4]);
            wt[kq * 4 + 0][r] = w4.x;
            wt[kq * 4 + 1][r] = w4.y;
            wt[kq * 4 + 2][r] = w4.z;
            wt[kq * 4 + 3][r] = w4.w;
        }
        __syncthreads();

        #pragma unroll 8
        for (int k = 0; k < 64; ++k) {
            float4 a  = *reinterpret_cast<const float4*>(&xst[k][ty * 4]);
            float4 bb = *reinterpret_cast<const float4*>(&wt[k][tx * 4]);
            float av[4] = {a.x, a.y, a.z, a.w};
            float bv[4] = {bb.x, bb.y, bb.z, bb.w};
            #pragma unroll
            for (int i = 0; i < 4; ++i)
                #pragma unroll
                for (int j = 0; j < 4; ++j)
                    acc[i][j] += av[i] * bv[j];
        }
    }

    float att0[4], att1[4], bv[4];
    #pragma unroll
    for (int j = 0; j < 4; ++j) {
        int c = tx * 4 + j;
        att0[j] = att[c * 2 + 0];
        att1[j] = att[c * 2 + 1];
        bv[j]   = bias[c];
    }

    float p0[4], p1[4];
    #pragma unroll
    for (int i = 0; i < 4; ++i) {
        int gr = row0 + ty * 4 + i;
        float f0 = acc[i][0] + bv[0];
        float f1 = acc[i][1] + bv[1];
        float f2 = acc[i][2] + bv[2];
        float f3 = acc[i][3] + bv[3];
        p0[i] = f0 * att0[0] + f1 * att0[1] + f2 * att0[2] + f3 * att0[3];
        p1[i] = f0 * att1[0] + f1 * att1[1] + f2 * att1[2] + f3 * att1[3];
        if (gr < N_NODES) {
            *reinterpret_cast<float4*>(&feature[gr * OUT_CH + tx * 4]) =
                make_float4(f0, f1, f2, f3);
        }
    }

    #pragma unroll
    for (int m = 1; m < 16; m <<= 1) {
        #pragma unroll
        for (int i = 0; i < 4; ++i) {
            p0[i] += __shfl_xor(p0[i], m, 64);
            p1[i] += __shfl_xor(p1[i], m, 64);
        }
    }
    if (tx == 0) {
        #pragma unroll
        for (int i = 0; i < 4; ++i) {
            int gr = row0 + ty * 4 + i;
            if (gr < N_NODES) {
                float z = p0[i] + p1[i];
                float lr = z > 0.f ? z : NEG_SLOPE * z;
                e0[gr] = p0[i];
                e1[gr] = p1[i];
                denom[gr] = expf(lr);   // self term; edge terms atomically added in k_fill
            }
        }
    }
}

// ---------------------------------------------------------------------------
// Kernel B: histogram of incoming-edge counts per target
// ---------------------------------------------------------------------------
__global__ __launch_bounds__(256) void k_hist(
    const int* __restrict__ ei, int* __restrict__ deg)
{
    int e = blockIdx.x * blockDim.x + threadIdx.x;
    if (e >= N_EDGES) return;
    atomicAdd(&deg[ei[e]], 1);
}

// ---------------------------------------------------------------------------
// Kernel C: single-block exclusive scan deg -> off (and cursor copy)
// 1024 threads, each owns a contiguous chunk of C elements.
// ---------------------------------------------------------------------------
__global__ __launch_bounds__(1024) void k_scan(
    const int* __restrict__ deg, int* __restrict__ off, int* __restrict__ cursor)
{
    __shared__ int sums[1024];
    const int tid = threadIdx.x;
    const int C = (N_NODES + 1023) / 1024;   // 49
    const int base = tid * C;

    int s = 0;
    for (int j = 0; j < C; ++j) {
        int i = base + j;
        if (i < N_NODES) s += deg[i];
    }
    sums[tid] = s;
    __syncthreads();
    for (int d = 1; d < 1024; d <<= 1) {
        int v = (tid >= d) ? sums[tid - d] : 0;
        __syncthreads();
        sums[tid] += v;
        __syncthreads();
    }
    int run = sums[tid] - s;                 // exclusive prefix of this chunk
    for (int j = 0; j < C; ++j) {
        int i = base + j;
        if (i < N_NODES) {
            off[i] = run;
            cursor[i] = run;
            run += deg[i];
        }
    }
    if (tid == 0) off[N_NODES] = N_EDGES;
}

// ---------------------------------------------------------------------------
// Kernel D: per-edge weight + CSR fill (src, w) grouped by target.
// Also accumulates denom[tar].
// ---------------------------------------------------------------------------
__global__ __launch_bounds__(256) void k_fill(
    const int* __restrict__ ei, const float* __restrict__ e0,
    const float* __restrict__ e1, float* __restrict__ denom,
    int* __restrict__ cursor, float2* __restrict__ edata)
{
    int e = blockIdx.x * blockDim.x + threadIdx.x;
    if (e >= N_EDGES) return;
    int tnode = ei[e];
    int snode = ei[N_EDGES + e];
    float z  = e0[tnode] + e1[snode];
    float lr = z > 0.f ? z : NEG_SLOPE * z;
    float w  = expf(lr);
    atomicAdd(&denom[tnode], w);
    int slot = atomicAdd(&cursor[tnode], 1);
    edata[slot] = make_float2(__int_as_float(snode), w);
}

// ---------------------------------------------------------------------------
// Kernel E: gather — one wave per target node, lane = channel.
// out[t][c] = alpha_self*feature[t][c] + sum_e alpha_e*feature[src_e][c]
// No atomics; single coalesced 256B store per node.
// ---------------------------------------------------------------------------
__global__ __launch_bounds__(256) void k_gather(
    const float* __restrict__ e0, const float* __restrict__ e1,
    const float* __restrict__ denom, const float* __restrict__ feature,
    const int* __restrict__ off, const float2* __restrict__ edata,
    float* __restrict__ out)
{
    int t = blockIdx.x * 4 + (threadIdx.x >> 6);   // wave id = node
    int c = threadIdx.x & 63;
    if (t >= N_NODES) return;

    float rden = 1.0f / denom[t];
    float z  = e0[t] + e1[t];
    float lr = z > 0.f ? z : NEG_SLOPE * z;
    float acc = expf(lr) * rden * feature[(size_t)t * OUT_CH + c];

    int e   = off[t];
    int end = off[t + 1];
    for (; e + 2 <= end; e += 2) {
        float2 d0 = edata[e];
        float2 d1 = edata[e + 1];
        int s0 = __float_as_int(d0.x);
        int s1 = __float_as_int(d1.x);
        float f0 = feature[(size_t)s0 * OUT_CH + c];
        float f1 = feature[(size_t)s1 * OUT_CH + c];
        acc += d0.y * rden * f0;
        acc += d1.y * rden * f1;
    }
    if (e < end) {
        float2 d = edata[e];
        int s0 = __float_as_int(d.x);
        acc += d.y * rden * feature[(size_t)s0 * OUT_CH + c];
    }
    out[(size_t)t * OUT_CH + c] = acc;
}

// ---------------------------------------------------------------------------
extern "C" void kernel_launch(void* const* d_in, const int* in_sizes, int n_in,
                              void* d_out, int out_size, void* d_ws, size_t ws_size,
                              hipStream_t stream)
{
    const float* x    = (const float*)d_in[0];
    const int*   ei   = (const int*)d_in[1];
    const float* W    = (const float*)d_in[2];
    const float* bias = (const float*)d_in[3];
    const float* att  = (const float*)d_in[4];
    float* out = (float*)d_out;

    // workspace layout:
    // feature[N*64] f32 | e0[N] | e1[N] | denom[N] | edata[E] float2 |
    // deg[N] i32 | off[N+1] i32 | cursor[N] i32
    float*  ws      = (float*)d_ws;
    float*  feature = ws;
    float*  e0      = feature + (size_t)N_NODES * OUT_CH;
    float*  e1      = e0 + N_NODES;
    float*  denom   = e1 + N_NODES;
    float2* edata   = (float2*)(denom + N_NODES);      // offset is even -> 8B aligned
    int*    deg     = (int*)(edata + N_EDGES);
    int*    off     = deg + N_NODES;
    int*    cursor  = off + N_NODES + 1;

    dim3 blk(256);

    k_gemm<<<dim3((N_NODES + 63) / 64), blk, 0, stream>>>(
        x, W, bias, att, feature, e0, e1, denom, deg);

    k_hist<<<dim3((N_EDGES + 255) / 256), blk, 0, stream>>>(ei, deg);

    k_scan<<<dim3(1), dim3(1024), 0, stream>>>(deg, off, cursor);

    k_fill<<<dim3((N_EDGES + 255) / 256), blk, 0, stream>>>(
        ei, e0, e1, denom, cursor, edata);

    k_gather<<<dim3((N_NODES + 3) / 4), blk, 0, stream>>>(
        e0, e1, denom, feature, off, edata, out);
}

// Round 3
// 293.842 us; speedup vs baseline: 1.3960x; 1.3960x over previous
//
#include <hip/hip_runtime.h>
#include <math.h>

#define N_NODES 50000
#define N_EDGES 800000
#define IN_CH 256
#define OUT_CH 64
#define NEG_SLOPE 0.2f

#define SCAN_BLK 256
#define N_SCAN_BLKS ((N_NODES + SCAN_BLK - 1) / SCAN_BLK)   // 196

// ---------------------------------------------------------------------------
// Kernel A: feature = x @ W^T + b  (M=50000, K=256, N=64)
// Fused epilogue: e0[n], e1[n] (att partials), denom[n] = exp(lrelu(e0+e1))
// (self-loop softmax term). Also zero-initializes deg[] (ws is poisoned).
// ---------------------------------------------------------------------------
__global__ __launch_bounds__(256) void k_gemm(
    const float* __restrict__ x, const float* __restrict__ W,
    const float* __restrict__ bias, const float* __restrict__ att,
    float* __restrict__ feature, float* __restrict__ e0,
    float* __restrict__ e1, float* __restrict__ denom,
    int* __restrict__ deg)
{
    constexpr int LDP = 68;
    __shared__ float xst[64][LDP];          // [k][row]
    __shared__ float wt[64][LDP];           // [k][col]

    const int t  = threadIdx.x;
    const int tx = t & 15;
    const int ty = t >> 4;
    const int row0 = blockIdx.x * 64;

    if (t < 64 && row0 + t < N_NODES) deg[row0 + t] = 0;

    float acc[4][4] = {};

    for (int kc = 0; kc < IN_CH; kc += 64) {
        __syncthreads();
        #pragma unroll
        for (int i = 0; i < 4; ++i) {
            int quad = t + i * 256;
            int r    = quad >> 4;
            int kq   = quad & 15;
            float4 v = make_float4(0.f, 0.f, 0.f, 0.f);
            int gr = row0 + r;
            if (gr < N_NODES)
                v = *reinterpret_cast<const float4*>(&x[gr * IN_CH + kc + kq * 4]);
            xst[kq * 4 + 0][r] = v.x;
            xst[kq * 4 + 1][r] = v.y;
            xst[kq * 4 + 2][r] = v.z;
            xst[kq * 4 + 3][r] = v.w;
            float4 w4 = *reinterpret_cast<const float4*>(&W[r * IN_CH + kc + kq * 4]);
            wt[kq * 4 + 0][r] = w4.x;
            wt[kq * 4 + 1][r] = w4.y;
            wt[kq * 4 + 2][r] = w4.z;
            wt[kq * 4 + 3][r] = w4.w;
        }
        __syncthreads();

        #pragma unroll 8
        for (int k = 0; k < 64; ++k) {
            float4 a  = *reinterpret_cast<const float4*>(&xst[k][ty * 4]);
            float4 bb = *reinterpret_cast<const float4*>(&wt[k][tx * 4]);
            float av[4] = {a.x, a.y, a.z, a.w};
            float bv[4] = {bb.x, bb.y, bb.z, bb.w};
            #pragma unroll
            for (int i = 0; i < 4; ++i)
                #pragma unroll
                for (int j = 0; j < 4; ++j)
                    acc[i][j] += av[i] * bv[j];
        }
    }

    float att0[4], att1[4], bv[4];
    #pragma unroll
    for (int j = 0; j < 4; ++j) {
        int c = tx * 4 + j;
        att0[j] = att[c * 2 + 0];
        att1[j] = att[c * 2 + 1];
        bv[j]   = bias[c];
    }

    float p0[4], p1[4];
    #pragma unroll
    for (int i = 0; i < 4; ++i) {
        int gr = row0 + ty * 4 + i;
        float f0 = acc[i][0] + bv[0];
        float f1 = acc[i][1] + bv[1];
        float f2 = acc[i][2] + bv[2];
        float f3 = acc[i][3] + bv[3];
        p0[i] = f0 * att0[0] + f1 * att0[1] + f2 * att0[2] + f3 * att0[3];
        p1[i] = f0 * att1[0] + f1 * att1[1] + f2 * att1[2] + f3 * att1[3];
        if (gr < N_NODES) {
            *reinterpret_cast<float4*>(&feature[gr * OUT_CH + tx * 4]) =
                make_float4(f0, f1, f2, f3);
        }
    }

    #pragma unroll
    for (int m = 1; m < 16; m <<= 1) {
        #pragma unroll
        for (int i = 0; i < 4; ++i) {
            p0[i] += __shfl_xor(p0[i], m, 64);
            p1[i] += __shfl_xor(p1[i], m, 64);
        }
    }
    if (tx == 0) {
        #pragma unroll
        for (int i = 0; i < 4; ++i) {
            int gr = row0 + ty * 4 + i;
            if (gr < N_NODES) {
                float z = p0[i] + p1[i];
                float lr = z > 0.f ? z : NEG_SLOPE * z;
                e0[gr] = p0[i];
                e1[gr] = p1[i];
                denom[gr] = expf(lr);   // self term; edge terms added in k_fill
            }
        }
    }
}

// ---------------------------------------------------------------------------
// Kernel B: histogram of incoming-edge counts per target
// ---------------------------------------------------------------------------
__global__ __launch_bounds__(256) void k_hist(
    const int* __restrict__ ei, int* __restrict__ deg)
{
    int e = blockIdx.x * blockDim.x + threadIdx.x;
    if (e >= N_EDGES) return;
    atomicAdd(&deg[ei[e]], 1);
}

// ---------------------------------------------------------------------------
// Scan pass 1: per-block exclusive scan of deg (256/block) -> off (local),
// block total -> bsum[blk]
// ---------------------------------------------------------------------------
__global__ __launch_bounds__(SCAN_BLK) void k_scan_blk(
    const int* __restrict__ deg, int* __restrict__ off, int* __restrict__ bsum)
{
    __shared__ int s[SCAN_BLK];
    int tid = threadIdx.x;
    int i = blockIdx.x * SCAN_BLK + tid;
    int v = (i < N_NODES) ? deg[i] : 0;
    s[tid] = v;
    __syncthreads();
    #pragma unroll
    for (int d = 1; d < SCAN_BLK; d <<= 1) {
        int u = (tid >= d) ? s[tid - d] : 0;
        __syncthreads();
        s[tid] += u;
        __syncthreads();
    }
    if (i < N_NODES) off[i] = s[tid] - v;          // exclusive, local to block
    if (tid == SCAN_BLK - 1) bsum[blockIdx.x] = s[tid];
}

// ---------------------------------------------------------------------------
// Scan pass 2: single block scans the 196 block sums -> boff (exclusive)
// ---------------------------------------------------------------------------
__global__ __launch_bounds__(256) void k_scan_top(
    const int* __restrict__ bsum, int* __restrict__ boff)
{
    __shared__ int s[256];
    int tid = threadIdx.x;
    int v = (tid < N_SCAN_BLKS) ? bsum[tid] : 0;
    s[tid] = v;
    __syncthreads();
    #pragma unroll
    for (int d = 1; d < 256; d <<= 1) {
        int u = (tid >= d) ? s[tid - d] : 0;
        __syncthreads();
        s[tid] += u;
        __syncthreads();
    }
    if (tid < N_SCAN_BLKS) boff[tid] = s[tid] - v;
}

// ---------------------------------------------------------------------------
// Scan pass 3: add block offsets, emit cursor copy, off[N]=E
// ---------------------------------------------------------------------------
__global__ __launch_bounds__(SCAN_BLK) void k_scan_add(
    int* __restrict__ off, const int* __restrict__ boff, int* __restrict__ cursor)
{
    int i = blockIdx.x * SCAN_BLK + threadIdx.x;
    if (i < N_NODES) {
        int o = off[i] + boff[blockIdx.x];
        off[i] = o;
        cursor[i] = o;
    }
    if (i == 0) off[N_NODES] = N_EDGES;
}

// ---------------------------------------------------------------------------
// Kernel D: per-edge weight + CSR fill (src, w) grouped by target.
// Also accumulates denom[tar].
// ---------------------------------------------------------------------------
__global__ __launch_bounds__(256) void k_fill(
    const int* __restrict__ ei, const float* __restrict__ e0,
    const float* __restrict__ e1, float* __restrict__ denom,
    int* __restrict__ cursor, float2* __restrict__ edata)
{
    int e = blockIdx.x * blockDim.x + threadIdx.x;
    if (e >= N_EDGES) return;
    int tnode = ei[e];
    int snode = ei[N_EDGES + e];
    float z  = e0[tnode] + e1[snode];
    float lr = z > 0.f ? z : NEG_SLOPE * z;
    float w  = expf(lr);
    atomicAdd(&denom[tnode], w);
    int slot = atomicAdd(&cursor[tnode], 1);
    edata[slot] = make_float2(__int_as_float(snode), w);
}

// ---------------------------------------------------------------------------
// Kernel E: gather — one wave per target node, lane = channel.
// ---------------------------------------------------------------------------
__global__ __launch_bounds__(256) void k_gather(
    const float* __restrict__ e0, const float* __restrict__ e1,
    const float* __restrict__ denom, const float* __restrict__ feature,
    const int* __restrict__ off, const float2* __restrict__ edata,
    float* __restrict__ out)
{
    int t = blockIdx.x * 4 + (threadIdx.x >> 6);   // wave id = node
    int c = threadIdx.x & 63;
    if (t >= N_NODES) return;

    float rden = 1.0f / denom[t];
    float z  = e0[t] + e1[t];
    float lr = z > 0.f ? z : NEG_SLOPE * z;
    float acc = expf(lr) * rden * feature[(size_t)t * OUT_CH + c];

    int e   = off[t];
    int end = off[t + 1];
    for (; e + 2 <= end; e += 2) {
        float2 d0 = edata[e];
        float2 d1 = edata[e + 1];
        int s0 = __float_as_int(d0.x);
        int s1 = __float_as_int(d1.x);
        float f0 = feature[(size_t)s0 * OUT_CH + c];
        float f1 = feature[(size_t)s1 * OUT_CH + c];
        acc += d0.y * rden * f0;
        acc += d1.y * rden * f1;
    }
    if (e < end) {
        float2 d = edata[e];
        int s0 = __float_as_int(d.x);
        acc += d.y * rden * feature[(size_t)s0 * OUT_CH + c];
    }
    out[(size_t)t * OUT_CH + c] = acc;
}

// ---------------------------------------------------------------------------
extern "C" void kernel_launch(void* const* d_in, const int* in_sizes, int n_in,
                              void* d_out, int out_size, void* d_ws, size_t ws_size,
                              hipStream_t stream)
{
    const float* x    = (const float*)d_in[0];
    const int*   ei   = (const int*)d_in[1];
    const float* W    = (const float*)d_in[2];
    const float* bias = (const float*)d_in[3];
    const float* att  = (const float*)d_in[4];
    float* out = (float*)d_out;

    // workspace layout:
    // feature[N*64] f32 | e0[N] | e1[N] | denom[N] | edata[E] float2 |
    // deg[N] i32 | off[N+1] i32 | cursor[N] i32 | bsum[196] | boff[196]
    float*  ws      = (float*)d_ws;
    float*  feature = ws;
    float*  e0      = feature + (size_t)N_NODES * OUT_CH;
    float*  e1      = e0 + N_NODES;
    float*  denom   = e1 + N_NODES;
    float2* edata   = (float2*)(denom + N_NODES);
    int*    deg     = (int*)(edata + N_EDGES);
    int*    off     = deg + N_NODES;
    int*    cursor  = off + N_NODES + 1;
    int*    bsum    = cursor + N_NODES;
    int*    boff    = bsum + N_SCAN_BLKS;

    dim3 blk(256);

    k_gemm<<<dim3((N_NODES + 63) / 64), blk, 0, stream>>>(
        x, W, bias, att, feature, e0, e1, denom, deg);

    k_hist<<<dim3((N_EDGES + 255) / 256), blk, 0, stream>>>(ei, deg);

    k_scan_blk<<<dim3(N_SCAN_BLKS), dim3(SCAN_BLK), 0, stream>>>(deg, off, bsum);
    k_scan_top<<<dim3(1), dim3(256), 0, stream>>>(bsum, boff);
    k_scan_add<<<dim3(N_SCAN_BLKS), dim3(SCAN_BLK), 0, stream>>>(off, boff, cursor);

    k_fill<<<dim3((N_EDGES + 255) / 256), blk, 0, stream>>>(
        ei, e0, e1, denom, cursor, edata);

    k_gather<<<dim3((N_NODES + 3) / 4), blk, 0, stream>>>(
        e0, e1, denom, feature, off, edata, out);
}

// Round 4
// 233.204 us; speedup vs baseline: 1.7590x; 1.2600x over previous
//
#include <hip/hip_runtime.h>
#include <math.h>

#define N_NODES 50000
#define N_EDGES 800000
#define IN_CH 256
#define OUT_CH 64
#define NEG_SLOPE 0.2f

#define SCAN_BLK 256
#define N_SCAN_BLKS ((N_NODES + SCAN_BLK - 1) / SCAN_BLK)   // 196

// ---------------------------------------------------------------------------
// Kernel A: feature = x @ W^T + b  (M=50000, K=256, N=64)
// Fused epilogue: e0[n], e1[n] (att partials). Zero-inits deg[] (ws poisoned).
// ---------------------------------------------------------------------------
__global__ __launch_bounds__(256) void k_gemm(
    const float* __restrict__ x, const float* __restrict__ W,
    const float* __restrict__ bias, const float* __restrict__ att,
    float* __restrict__ feature, float* __restrict__ e0,
    float* __restrict__ e1, int* __restrict__ deg)
{
    constexpr int LDP = 68;
    __shared__ float xst[64][LDP];          // [k][row]
    __shared__ float wt[64][LDP];           // [k][col]

    const int t  = threadIdx.x;
    const int tx = t & 15;
    const int ty = t >> 4;
    const int row0 = blockIdx.x * 64;

    if (t < 64 && row0 + t < N_NODES) deg[row0 + t] = 0;

    float acc[4][4] = {};

    for (int kc = 0; kc < IN_CH; kc += 64) {
        __syncthreads();
        #pragma unroll
        for (int i = 0; i < 4; ++i) {
            int quad = t + i * 256;
            int r    = quad >> 4;
            int kq   = quad & 15;
            float4 v = make_float4(0.f, 0.f, 0.f, 0.f);
            int gr = row0 + r;
            if (gr < N_NODES)
                v = *reinterpret_cast<const float4*>(&x[gr * IN_CH + kc + kq * 4]);
            xst[kq * 4 + 0][r] = v.x;
            xst[kq * 4 + 1][r] = v.y;
            xst[kq * 4 + 2][r] = v.z;
            xst[kq * 4 + 3][r] = v.w;
            float4 w4 = *reinterpret_cast<const float4*>(&W[r * IN_CH + kc + kq * 4]);
            wt[kq * 4 + 0][r] = w4.x;
            wt[kq * 4 + 1][r] = w4.y;
            wt[kq * 4 + 2][r] = w4.z;
            wt[kq * 4 + 3][r] = w4.w;
        }
        __syncthreads();

        #pragma unroll 8
        for (int k = 0; k < 64; ++k) {
            float4 a  = *reinterpret_cast<const float4*>(&xst[k][ty * 4]);
            float4 bb = *reinterpret_cast<const float4*>(&wt[k][tx * 4]);
            float av[4] = {a.x, a.y, a.z, a.w};
            float bv[4] = {bb.x, bb.y, bb.z, bb.w};
            #pragma unroll
            for (int i = 0; i < 4; ++i)
                #pragma unroll
                for (int j = 0; j < 4; ++j)
                    acc[i][j] += av[i] * bv[j];
        }
    }

    float att0[4], att1[4], bv[4];
    #pragma unroll
    for (int j = 0; j < 4; ++j) {
        int c = tx * 4 + j;
        att0[j] = att[c * 2 + 0];
        att1[j] = att[c * 2 + 1];
        bv[j]   = bias[c];
    }

    float p0[4], p1[4];
    #pragma unroll
    for (int i = 0; i < 4; ++i) {
        int gr = row0 + ty * 4 + i;
        float f0 = acc[i][0] + bv[0];
        float f1 = acc[i][1] + bv[1];
        float f2 = acc[i][2] + bv[2];
        float f3 = acc[i][3] + bv[3];
        p0[i] = f0 * att0[0] + f1 * att0[1] + f2 * att0[2] + f3 * att0[3];
        p1[i] = f0 * att1[0] + f1 * att1[1] + f2 * att1[2] + f3 * att1[3];
        if (gr < N_NODES) {
            *reinterpret_cast<float4*>(&feature[gr * OUT_CH + tx * 4]) =
                make_float4(f0, f1, f2, f3);
        }
    }

    #pragma unroll
    for (int m = 1; m < 16; m <<= 1) {
        #pragma unroll
        for (int i = 0; i < 4; ++i) {
            p0[i] += __shfl_xor(p0[i], m, 64);
            p1[i] += __shfl_xor(p1[i], m, 64);
        }
    }
    if (tx == 0) {
        #pragma unroll
        for (int i = 0; i < 4; ++i) {
            int gr = row0 + ty * 4 + i;
            if (gr < N_NODES) {
                e0[gr] = p0[i];
                e1[gr] = p1[i];
            }
        }
    }
}

// ---------------------------------------------------------------------------
// Kernel B: histogram + local slot assignment.
// e_slot[e] = old count of tar — position of edge e within its target's
// segment. The ONLY per-edge atomic in the whole pipeline.
// ---------------------------------------------------------------------------
__global__ __launch_bounds__(256) void k_hist(
    const int* __restrict__ ei, int* __restrict__ deg, int* __restrict__ e_slot)
{
    int e = blockIdx.x * blockDim.x + threadIdx.x;
    if (e >= N_EDGES) return;
    e_slot[e] = atomicAdd(&deg[ei[e]], 1);
}

// ---------------------------------------------------------------------------
// Scan pass 1: per-block exclusive scan of deg -> offl (block-local),
// block total -> bsum[blk]
// ---------------------------------------------------------------------------
__global__ __launch_bounds__(SCAN_BLK) void k_scan_blk(
    const int* __restrict__ deg, int* __restrict__ offl, int* __restrict__ bsum)
{
    __shared__ int s[SCAN_BLK];
    int tid = threadIdx.x;
    int i = blockIdx.x * SCAN_BLK + tid;
    int v = (i < N_NODES) ? deg[i] : 0;
    s[tid] = v;
    __syncthreads();
    #pragma unroll
    for (int d = 1; d < SCAN_BLK; d <<= 1) {
        int u = (tid >= d) ? s[tid - d] : 0;
        __syncthreads();
        s[tid] += u;
        __syncthreads();
    }
    if (i < N_NODES) offl[i] = s[tid] - v;
    if (tid == SCAN_BLK - 1) bsum[blockIdx.x] = s[tid];
}

// ---------------------------------------------------------------------------
// Scan pass 2: single block scans 196 block sums -> boff (exclusive),
// boff[N_SCAN_BLKS] = N_EDGES sentinel.
// ---------------------------------------------------------------------------
__global__ __launch_bounds__(256) void k_scan_top(
    const int* __restrict__ bsum, int* __restrict__ boff)
{
    __shared__ int s[256];
    int tid = threadIdx.x;
    int v = (tid < N_SCAN_BLKS) ? bsum[tid] : 0;
    s[tid] = v;
    __syncthreads();
    #pragma unroll
    for (int d = 1; d < 256; d <<= 1) {
        int u = (tid >= d) ? s[tid - d] : 0;
        __syncthreads();
        s[tid] += u;
        __syncthreads();
    }
    if (tid < N_SCAN_BLKS) boff[tid] = s[tid] - v;
    if (tid == 0) boff[N_SCAN_BLKS] = N_EDGES;
}

// ---------------------------------------------------------------------------
// Kernel D: per-edge weight + CSR fill — NO atomics.
// slot = offl[t] + boff[t>>8] + e_slot[e]
// ---------------------------------------------------------------------------
__global__ __launch_bounds__(256) void k_fill(
    const int* __restrict__ ei, const float* __restrict__ e0,
    const float* __restrict__ e1, const int* __restrict__ offl,
    const int* __restrict__ boff, const int* __restrict__ e_slot,
    float2* __restrict__ edata)
{
    int e = blockIdx.x * blockDim.x + threadIdx.x;
    if (e >= N_EDGES) return;
    int tnode = ei[e];
    int snode = ei[N_EDGES + e];
    float z  = e0[tnode] + e1[snode];
    float lr = z > 0.f ? z : NEG_SLOPE * z;
    float w  = expf(lr);
    int slot = offl[tnode] + boff[tnode >> 8] + e_slot[e];
    edata[slot] = make_float2(__int_as_float(snode), w);
}

// ---------------------------------------------------------------------------
// Kernel E: gather — one wave per target node, lane = channel.
// Denominator accumulated in-register (broadcast w, free on all lanes);
// single divide at the end. No atomics, one coalesced 256B store per node.
// ---------------------------------------------------------------------------
__global__ __launch_bounds__(256) void k_gather(
    const float* __restrict__ e0, const float* __restrict__ e1,
    const float* __restrict__ feature, const int* __restrict__ offl,
    const int* __restrict__ boff, const float2* __restrict__ edata,
    float* __restrict__ out)
{
    int t = blockIdx.x * 4 + (threadIdx.x >> 6);   // wave id = node
    int c = threadIdx.x & 63;
    if (t >= N_NODES) return;

    float z  = e0[t] + e1[t];
    float lr = z > 0.f ? z : NEG_SLOPE * z;
    float ws = expf(lr);                            // self weight

    float acc  = ws * feature[(size_t)t * OUT_CH + c];
    float wsum = ws;

    int e   = offl[t] + boff[t >> 8];
    int end;
    if (t + 1 < N_NODES) end = offl[t + 1] + boff[(t + 1) >> 8];
    else                 end = N_EDGES;

    for (; e + 2 <= end; e += 2) {
        float2 d0 = edata[e];
        float2 d1 = edata[e + 1];
        int s0 = __float_as_int(d0.x);
        int s1 = __float_as_int(d1.x);
        float f0 = feature[(size_t)s0 * OUT_CH + c];
        float f1 = feature[(size_t)s1 * OUT_CH + c];
        acc  += d0.y * f0;
        acc  += d1.y * f1;
        wsum += d0.y + d1.y;
    }
    if (e < end) {
        float2 d = edata[e];
        int s0 = __float_as_int(d.x);
        acc  += d.y * feature[(size_t)s0 * OUT_CH + c];
        wsum += d.y;
    }
    out[(size_t)t * OUT_CH + c] = acc / wsum;
}

// ---------------------------------------------------------------------------
extern "C" void kernel_launch(void* const* d_in, const int* in_sizes, int n_in,
                              void* d_out, int out_size, void* d_ws, size_t ws_size,
                              hipStream_t stream)
{
    const float* x    = (const float*)d_in[0];
    const int*   ei   = (const int*)d_in[1];
    const float* W    = (const float*)d_in[2];
    const float* bias = (const float*)d_in[3];
    const float* att  = (const float*)d_in[4];
    float* out = (float*)d_out;

    // workspace layout:
    // feature[N*64] f32 | e0[N] | e1[N] | edata[E] float2 |
    // deg[N] i32 | offl[N] i32 | bsum[196] | boff[197] | e_slot[E] i32
    float*  ws      = (float*)d_ws;
    float*  feature = ws;
    float*  e0      = feature + (size_t)N_NODES * OUT_CH;
    float*  e1      = e0 + N_NODES;
    float2* edata   = (float2*)(e1 + N_NODES);          // even offset -> 8B aligned
    int*    deg     = (int*)(edata + N_EDGES);
    int*    offl    = deg + N_NODES;
    int*    bsum    = offl + N_NODES;
    int*    boff    = bsum + N_SCAN_BLKS;
    int*    e_slot  = boff + N_SCAN_BLKS + 1;

    dim3 blk(256);

    k_gemm<<<dim3((N_NODES + 63) / 64), blk, 0, stream>>>(
        x, W, bias, att, feature, e0, e1, deg);

    k_hist<<<dim3((N_EDGES + 255) / 256), blk, 0, stream>>>(ei, deg, e_slot);

    k_scan_blk<<<dim3(N_SCAN_BLKS), dim3(SCAN_BLK), 0, stream>>>(deg, offl, bsum);
    k_scan_top<<<dim3(1), dim3(256), 0, stream>>>(bsum, boff);

    k_fill<<<dim3((N_EDGES + 255) / 256), blk, 0, stream>>>(
        ei, e0, e1, offl, boff, e_slot, edata);

    k_gather<<<dim3((N_NODES + 3) / 4), blk, 0, stream>>>(
        e0, e1, feature, offl, boff, edata, out);
}

// Round 5
// 199.170 us; speedup vs baseline: 2.0596x; 1.1709x over previous
//
#include <hip/hip_runtime.h>
#include <math.h>

#define N_NODES 50000
#define N_EDGES 800000
#define IN_CH 256
#define OUT_CH 64
#define NEG_SLOPE 0.2f

#define SCAN_BLK 256
#define N_SCAN_BLKS ((N_NODES + SCAN_BLK - 1) / SCAN_BLK)   // 196

typedef __bf16 bf16x4 __attribute__((ext_vector_type(4)));
typedef __bf16 bf16x8 __attribute__((ext_vector_type(8)));
typedef float  f32x4  __attribute__((ext_vector_type(4)));

// ---------------------------------------------------------------------------
// Kernel A: feature = x @ W^T + b via MFMA, split-bf16 (3-term) for fp32-level
// accuracy: x=xh+xl, W=Wh+Wl (bf16+residual); x@W^T ~= xh Wh + xl Wh + xh Wl.
// Block: 256 thr = 4 waves; tile 64 rows x 64 cols; K staged in chunks of 64.
// Wave w owns rows [16w,16w+16); 4 col-tiles of 16 via mfma_f32_16x16x32_bf16.
// Fused epilogue: e0/e1 (att partials); zero-inits deg[].
// LDS row stride 72 bf16 (144B) -> frag ds_read_b128 2-way max (free).
// ---------------------------------------------------------------------------
__global__ __launch_bounds__(256) void k_gemm(
    const float* __restrict__ x, const float* __restrict__ W,
    const float* __restrict__ bias, const float* __restrict__ att,
    float* __restrict__ feature, float* __restrict__ e0,
    float* __restrict__ e1, int* __restrict__ deg)
{
    __shared__ __bf16 Ah[64][72];
    __shared__ __bf16 Al[64][72];
    __shared__ __bf16 Bh[64][72];
    __shared__ __bf16 Bl[64][72];

    const int t    = threadIdx.x;
    const int row0 = blockIdx.x * 64;
    const int wv   = t >> 6;          // wave 0..3
    const int li   = t & 63;
    const int lm   = li & 15;         // frag row index
    const int lq   = li >> 4;         // frag quad

    if (t < 64 && row0 + t < N_NODES) deg[row0 + t] = 0;

    f32x4 acc[4];
    #pragma unroll
    for (int tn = 0; tn < 4; ++tn) acc[tn] = (f32x4){0.f, 0.f, 0.f, 0.f};

    const int sr = t >> 2;            // staging row 0..63
    const int cq = t & 3;             // staging col-quad (16 floats)

    for (int kc = 0; kc < IN_CH; kc += 64) {
        __syncthreads();
        // stage x tile (hi/lo split)
        {
            int gr = row0 + sr;
            #pragma unroll
            for (int i = 0; i < 4; ++i) {
                float4 v = make_float4(0.f, 0.f, 0.f, 0.f);
                if (gr < N_NODES)
                    v = *reinterpret_cast<const float4*>(&x[(size_t)gr * IN_CH + kc + cq * 16 + i * 4]);
                __bf16 hx = (__bf16)v.x, hy = (__bf16)v.y, hz = (__bf16)v.z, hw = (__bf16)v.w;
                bf16x4 h = {hx, hy, hz, hw};
                bf16x4 l = {(__bf16)(v.x - (float)hx), (__bf16)(v.y - (float)hy),
                            (__bf16)(v.z - (float)hz), (__bf16)(v.w - (float)hw)};
                *reinterpret_cast<bf16x4*>(&Ah[sr][cq * 16 + i * 4]) = h;
                *reinterpret_cast<bf16x4*>(&Al[sr][cq * 16 + i * 4]) = l;
            }
        }
        // stage W tile (hi/lo split); W is [64][256], rows = out channels
        {
            #pragma unroll
            for (int i = 0; i < 4; ++i) {
                float4 v = *reinterpret_cast<const float4*>(&W[(size_t)sr * IN_CH + kc + cq * 16 + i * 4]);
                __bf16 hx = (__bf16)v.x, hy = (__bf16)v.y, hz = (__bf16)v.z, hw = (__bf16)v.w;
                bf16x4 h = {hx, hy, hz, hw};
                bf16x4 l = {(__bf16)(v.x - (float)hx), (__bf16)(v.y - (float)hy),
                            (__bf16)(v.z - (float)hz), (__bf16)(v.w - (float)hw)};
                *reinterpret_cast<bf16x4*>(&Bh[sr][cq * 16 + i * 4]) = h;
                *reinterpret_cast<bf16x4*>(&Bl[sr][cq * 16 + i * 4]) = l;
            }
        }
        __syncthreads();

        #pragma unroll
        for (int half = 0; half < 2; ++half) {
            int kb = half * 32 + lq * 8;
            bf16x8 ah = *reinterpret_cast<const bf16x8*>(&Ah[wv * 16 + lm][kb]);
            bf16x8 al = *reinterpret_cast<const bf16x8*>(&Al[wv * 16 + lm][kb]);
            #pragma unroll
            for (int tn = 0; tn < 4; ++tn) {
                bf16x8 bh = *reinterpret_cast<const bf16x8*>(&Bh[tn * 16 + lm][kb]);
                bf16x8 bl = *reinterpret_cast<const bf16x8*>(&Bl[tn * 16 + lm][kb]);
                acc[tn] = __builtin_amdgcn_mfma_f32_16x16x32_bf16(ah, bh, acc[tn], 0, 0, 0);
                acc[tn] = __builtin_amdgcn_mfma_f32_16x16x32_bf16(al, bh, acc[tn], 0, 0, 0);
                acc[tn] = __builtin_amdgcn_mfma_f32_16x16x32_bf16(ah, bl, acc[tn], 0, 0, 0);
            }
        }
    }

    // epilogue: bias, store feature, att partials
    float att0[4], att1[4], bv[4];
    #pragma unroll
    for (int tn = 0; tn < 4; ++tn) {
        int c = tn * 16 + lm;
        att0[tn] = att[c * 2 + 0];
        att1[tn] = att[c * 2 + 1];
        bv[tn]   = bias[c];
    }

    float p0[4] = {0.f, 0.f, 0.f, 0.f};
    float p1[4] = {0.f, 0.f, 0.f, 0.f};
    #pragma unroll
    for (int r = 0; r < 4; ++r) {
        int row = row0 + wv * 16 + lq * 4 + r;   // D: row = quad*4+reg
        #pragma unroll
        for (int tn = 0; tn < 4; ++tn) {
            float f = acc[tn][r] + bv[tn];
            if (row < N_NODES)
                feature[(size_t)row * OUT_CH + tn * 16 + lm] = f;   // D: col = lane&15
            p0[r] += f * att0[tn];
            p1[r] += f * att1[tn];
        }
    }

    // reduce over the 16 lanes of the quad (masks 1..8 stay in-quad)
    #pragma unroll
    for (int m = 1; m < 16; m <<= 1) {
        #pragma unroll
        for (int r = 0; r < 4; ++r) {
            p0[r] += __shfl_xor(p0[r], m, 64);
            p1[r] += __shfl_xor(p1[r], m, 64);
        }
    }
    if (lm == 0) {
        #pragma unroll
        for (int r = 0; r < 4; ++r) {
            int row = row0 + wv * 16 + lq * 4 + r;
            if (row < N_NODES) {
                e0[row] = p0[r];
                e1[row] = p1[r];
            }
        }
    }
}

// ---------------------------------------------------------------------------
// Kernel B: histogram + local slot assignment (the only per-edge atomic).
// ---------------------------------------------------------------------------
__global__ __launch_bounds__(256) void k_hist(
    const int* __restrict__ ei, int* __restrict__ deg, int* __restrict__ e_slot)
{
    int e = blockIdx.x * blockDim.x + threadIdx.x;
    if (e >= N_EDGES) return;
    e_slot[e] = atomicAdd(&deg[ei[e]], 1);
}

// ---------------------------------------------------------------------------
// Scan pass 1: per-block exclusive scan of deg -> offl, block total -> bsum
// ---------------------------------------------------------------------------
__global__ __launch_bounds__(SCAN_BLK) void k_scan_blk(
    const int* __restrict__ deg, int* __restrict__ offl, int* __restrict__ bsum)
{
    __shared__ int s[SCAN_BLK];
    int tid = threadIdx.x;
    int i = blockIdx.x * SCAN_BLK + tid;
    int v = (i < N_NODES) ? deg[i] : 0;
    s[tid] = v;
    __syncthreads();
    #pragma unroll
    for (int d = 1; d < SCAN_BLK; d <<= 1) {
        int u = (tid >= d) ? s[tid - d] : 0;
        __syncthreads();
        s[tid] += u;
        __syncthreads();
    }
    if (i < N_NODES) offl[i] = s[tid] - v;
    if (tid == SCAN_BLK - 1) bsum[blockIdx.x] = s[tid];
}

// ---------------------------------------------------------------------------
// Scan pass 2: single block scans block sums -> boff (exclusive) + sentinel
// ---------------------------------------------------------------------------
__global__ __launch_bounds__(256) void k_scan_top(
    const int* __restrict__ bsum, int* __restrict__ boff)
{
    __shared__ int s[256];
    int tid = threadIdx.x;
    int v = (tid < N_SCAN_BLKS) ? bsum[tid] : 0;
    s[tid] = v;
    __syncthreads();
    #pragma unroll
    for (int d = 1; d < 256; d <<= 1) {
        int u = (tid >= d) ? s[tid - d] : 0;
        __syncthreads();
        s[tid] += u;
        __syncthreads();
    }
    if (tid < N_SCAN_BLKS) boff[tid] = s[tid] - v;
    if (tid == 0) boff[N_SCAN_BLKS] = N_EDGES;
}

// ---------------------------------------------------------------------------
// Kernel D: CSR fill — src index only, NO atomics, no math.
// ---------------------------------------------------------------------------
__global__ __launch_bounds__(256) void k_fill(
    const int* __restrict__ ei, const int* __restrict__ offl,
    const int* __restrict__ boff, const int* __restrict__ e_slot,
    int* __restrict__ csr)
{
    int e = blockIdx.x * blockDim.x + threadIdx.x;
    if (e >= N_EDGES) return;
    int tnode = ei[e];
    int snode = ei[N_EDGES + e];
    csr[offl[tnode] + boff[tnode >> 8] + e_slot[e]] = snode;
}

// ---------------------------------------------------------------------------
// Kernel E: gather — one wave per target, lane = channel. Edge weight
// computed inline (e1 is L2-resident; VALU idle). Unroll x4 for MLP.
// ---------------------------------------------------------------------------
__global__ __launch_bounds__(256) void k_gather(
    const float* __restrict__ e0, const float* __restrict__ e1,
    const float* __restrict__ feature, const int* __restrict__ offl,
    const int* __restrict__ boff, const int* __restrict__ csr,
    float* __restrict__ out)
{
    int t = blockIdx.x * 4 + (threadIdx.x >> 6);
    int c = threadIdx.x & 63;
    if (t >= N_NODES) return;

    float e0t = e0[t];
    float z   = e0t + e1[t];
    float lr  = z > 0.f ? z : NEG_SLOPE * z;
    float wsf = expf(lr);

    float acc  = wsf * feature[(size_t)t * OUT_CH + c];
    float wsum = wsf;

    int e   = offl[t] + boff[t >> 8];
    int end = (t + 1 < N_NODES) ? (offl[t + 1] + boff[(t + 1) >> 8]) : N_EDGES;

    for (; e + 4 <= end; e += 4) {
        int s0 = csr[e], s1 = csr[e + 1], s2 = csr[e + 2], s3 = csr[e + 3];
        float q0 = e1[s0], q1 = e1[s1], q2 = e1[s2], q3 = e1[s3];
        float f0 = feature[(size_t)s0 * OUT_CH + c];
        float f1 = feature[(size_t)s1 * OUT_CH + c];
        float f2 = feature[(size_t)s2 * OUT_CH + c];
        float f3 = feature[(size_t)s3 * OUT_CH + c];
        float z0 = e0t + q0, z1 = e0t + q1, z2 = e0t + q2, z3 = e0t + q3;
        float w0 = expf(z0 > 0.f ? z0 : NEG_SLOPE * z0);
        float w1 = expf(z1 > 0.f ? z1 : NEG_SLOPE * z1);
        float w2 = expf(z2 > 0.f ? z2 : NEG_SLOPE * z2);
        float w3 = expf(z3 > 0.f ? z3 : NEG_SLOPE * z3);
        acc += w0 * f0 + w1 * f1 + w2 * f2 + w3 * f3;
        wsum += (w0 + w1) + (w2 + w3);
    }
    for (; e < end; ++e) {
        int s0 = csr[e];
        float q0 = e1[s0];
        float f0 = feature[(size_t)s0 * OUT_CH + c];
        float z0 = e0t + q0;
        float w0 = expf(z0 > 0.f ? z0 : NEG_SLOPE * z0);
        acc += w0 * f0;
        wsum += w0;
    }
    out[(size_t)t * OUT_CH + c] = acc / wsum;
}

// ---------------------------------------------------------------------------
extern "C" void kernel_launch(void* const* d_in, const int* in_sizes, int n_in,
                              void* d_out, int out_size, void* d_ws, size_t ws_size,
                              hipStream_t stream)
{
    const float* x    = (const float*)d_in[0];
    const int*   ei   = (const int*)d_in[1];
    const float* W    = (const float*)d_in[2];
    const float* bias = (const float*)d_in[3];
    const float* att  = (const float*)d_in[4];
    float* out = (float*)d_out;

    // workspace layout:
    // feature[N*64] f32 | e0[N] | e1[N] | csr[E] i32 |
    // deg[N] i32 | offl[N] i32 | bsum[196] | boff[197] | e_slot[E] i32
    float* ws      = (float*)d_ws;
    float* feature = ws;
    float* e0      = feature + (size_t)N_NODES * OUT_CH;
    float* e1      = e0 + N_NODES;
    int*   csr     = (int*)(e1 + N_NODES);
    int*   deg     = csr + N_EDGES;
    int*   offl    = deg + N_NODES;
    int*   bsum    = offl + N_NODES;
    int*   boff    = bsum + N_SCAN_BLKS;
    int*   e_slot  = boff + N_SCAN_BLKS + 1;

    dim3 blk(256);

    k_gemm<<<dim3((N_NODES + 63) / 64), blk, 0, stream>>>(
        x, W, bias, att, feature, e0, e1, deg);

    k_hist<<<dim3((N_EDGES + 255) / 256), blk, 0, stream>>>(ei, deg, e_slot);

    k_scan_blk<<<dim3(N_SCAN_BLKS), dim3(SCAN_BLK), 0, stream>>>(deg, offl, bsum);
    k_scan_top<<<dim3(1), dim3(256), 0, stream>>>(bsum, boff);

    k_fill<<<dim3((N_EDGES + 255) / 256), blk, 0, stream>>>(
        ei, offl, boff, e_slot, csr);

    k_gather<<<dim3((N_NODES + 3) / 4), blk, 0, stream>>>(
        e0, e1, feature, offl, boff, csr, out);
}

// Round 7
// 197.896 us; speedup vs baseline: 2.0729x; 1.0064x over previous
//
#include <hip/hip_runtime.h>
#include <math.h>

#define N_NODES 50000
#define N_EDGES 800000
#define IN_CH 256
#define OUT_CH 64
#define NEG_SLOPE 0.2f

#define SCAN_BLK 256
#define N_SCAN_BLKS ((N_NODES + SCAN_BLK - 1) / SCAN_BLK)   // 196

typedef __bf16 bf16x4 __attribute__((ext_vector_type(4)));
typedef __bf16 bf16x8 __attribute__((ext_vector_type(8)));
typedef float  f32x4  __attribute__((ext_vector_type(4)));

// ---------------------------------------------------------------------------
// Kernel A: feature = x @ W^T + b via bf16 MFMA (inputs rounded to bf16,
// fp32 accumulate). Full-K LDS staging: A,B tiles 64x256 bf16, row stride
// 264 (528B) -> b128-aligned, benign 2-way bank aliasing. One barrier.
// Staging: thread owns row t>>2, 64-float chunk (t&3)*64; j*i loop covers
// all 256 floats per row exactly once (fixed from R6's half-coverage bug).
// Epilogue: bf16 feature store, e0/e1 att partials; zero-inits deg[].
// ---------------------------------------------------------------------------
__global__ __launch_bounds__(256) void k_gemm(
    const float* __restrict__ x, const float* __restrict__ W,
    const float* __restrict__ bias, const float* __restrict__ att,
    __bf16* __restrict__ featb, float* __restrict__ e0,
    float* __restrict__ e1, int* __restrict__ deg)
{
    __shared__ __bf16 A[64][264];
    __shared__ __bf16 B[64][264];

    const int t    = threadIdx.x;
    const int row0 = blockIdx.x * 64;
    const int wv   = t >> 6;          // wave 0..3
    const int li   = t & 63;
    const int lm   = li & 15;         // frag m/n index
    const int lq   = li >> 4;         // frag quad

    if (t < 64 && row0 + t < N_NODES) deg[row0 + t] = 0;

    // ---- stage x and W tiles (fp32 -> bf16) ----
    const int sr = t >> 2;            // row 0..63
    const int cq = t & 3;             // 64-float chunk selector
    {
        int gr = row0 + sr;
        bool ok = (gr < N_NODES);
        #pragma unroll
        for (int j = 0; j < 4; ++j) {
            #pragma unroll
            for (int i = 0; i < 4; ++i) {
                int kk = j * 64 + cq * 16 + i * 4;
                float4 v = make_float4(0.f, 0.f, 0.f, 0.f);
                if (ok)
                    v = *reinterpret_cast<const float4*>(&x[(size_t)gr * IN_CH + kk]);
                bf16x4 h = {(__bf16)v.x, (__bf16)v.y, (__bf16)v.z, (__bf16)v.w};
                *reinterpret_cast<bf16x4*>(&A[sr][kk]) = h;

                float4 w1 = *reinterpret_cast<const float4*>(&W[(size_t)sr * IN_CH + kk]);
                bf16x4 g = {(__bf16)w1.x, (__bf16)w1.y, (__bf16)w1.z, (__bf16)w1.w};
                *reinterpret_cast<bf16x4*>(&B[sr][kk]) = g;
            }
        }
    }
    __syncthreads();

    // ---- MFMA main loop: 8 K-chunks of 32 ----
    f32x4 acc[4];
    #pragma unroll
    for (int tn = 0; tn < 4; ++tn) acc[tn] = (f32x4){0.f, 0.f, 0.f, 0.f};

    #pragma unroll
    for (int kb = 0; kb < 8; ++kb) {
        int ko = kb * 32 + lq * 8;
        bf16x8 a = *reinterpret_cast<const bf16x8*>(&A[wv * 16 + lm][ko]);
        #pragma unroll
        for (int tn = 0; tn < 4; ++tn) {
            bf16x8 b = *reinterpret_cast<const bf16x8*>(&B[tn * 16 + lm][ko]);
            acc[tn] = __builtin_amdgcn_mfma_f32_16x16x32_bf16(a, b, acc[tn], 0, 0, 0);
        }
    }

    // ---- epilogue ----
    float att0[4], att1[4], bv[4];
    #pragma unroll
    for (int tn = 0; tn < 4; ++tn) {
        int c = tn * 16 + lm;
        att0[tn] = att[c * 2 + 0];
        att1[tn] = att[c * 2 + 1];
        bv[tn]   = bias[c];
    }

    float p0[4] = {0.f, 0.f, 0.f, 0.f};
    float p1[4] = {0.f, 0.f, 0.f, 0.f};
    #pragma unroll
    for (int r = 0; r < 4; ++r) {
        int row = row0 + wv * 16 + lq * 4 + r;   // D: row = quad*4+reg
        #pragma unroll
        for (int tn = 0; tn < 4; ++tn) {
            float f = acc[tn][r] + bv[tn];
            if (row < N_NODES)
                featb[(size_t)row * OUT_CH + tn * 16 + lm] = (__bf16)f;  // col = lane&15
            p0[r] += f * att0[tn];
            p1[r] += f * att1[tn];
        }
    }

    #pragma unroll
    for (int m = 1; m < 16; m <<= 1) {
        #pragma unroll
        for (int r = 0; r < 4; ++r) {
            p0[r] += __shfl_xor(p0[r], m, 64);
            p1[r] += __shfl_xor(p1[r], m, 64);
        }
    }
    if (lm == 0) {
        #pragma unroll
        for (int r = 0; r < 4; ++r) {
            int row = row0 + wv * 16 + lq * 4 + r;
            if (row < N_NODES) {
                e0[row] = p0[r];
                e1[row] = p1[r];
            }
        }
    }
}

// ---------------------------------------------------------------------------
// Kernel B: histogram + local slot assignment (the only per-edge atomic).
// ---------------------------------------------------------------------------
__global__ __launch_bounds__(256) void k_hist(
    const int* __restrict__ ei, int* __restrict__ deg, int* __restrict__ e_slot)
{
    int e = blockIdx.x * blockDim.x + threadIdx.x;
    if (e >= N_EDGES) return;
    e_slot[e] = atomicAdd(&deg[ei[e]], 1);
}

// ---------------------------------------------------------------------------
// Scan pass 1: per-block exclusive scan of deg -> offl, block total -> bsum
// ---------------------------------------------------------------------------
__global__ __launch_bounds__(SCAN_BLK) void k_scan_blk(
    const int* __restrict__ deg, int* __restrict__ offl, int* __restrict__ bsum)
{
    __shared__ int s[SCAN_BLK];
    int tid = threadIdx.x;
    int i = blockIdx.x * SCAN_BLK + tid;
    int v = (i < N_NODES) ? deg[i] : 0;
    s[tid] = v;
    __syncthreads();
    #pragma unroll
    for (int d = 1; d < SCAN_BLK; d <<= 1) {
        int u = (tid >= d) ? s[tid - d] : 0;
        __syncthreads();
        s[tid] += u;
        __syncthreads();
    }
    if (i < N_NODES) offl[i] = s[tid] - v;
    if (tid == SCAN_BLK - 1) bsum[blockIdx.x] = s[tid];
}

// ---------------------------------------------------------------------------
// Scan pass 2: single block scans block sums -> boff (exclusive) + sentinel
// ---------------------------------------------------------------------------
__global__ __launch_bounds__(256) void k_scan_top(
    const int* __restrict__ bsum, int* __restrict__ boff)
{
    __shared__ int s[256];
    int tid = threadIdx.x;
    int v = (tid < N_SCAN_BLKS) ? bsum[tid] : 0;
    s[tid] = v;
    __syncthreads();
    #pragma unroll
    for (int d = 1; d < 256; d <<= 1) {
        int u = (tid >= d) ? s[tid - d] : 0;
        __syncthreads();
        s[tid] += u;
        __syncthreads();
    }
    if (tid < N_SCAN_BLKS) boff[tid] = s[tid] - v;
    if (tid == 0) boff[N_SCAN_BLKS] = N_EDGES;
}

// ---------------------------------------------------------------------------
// Kernel D: CSR fill — src index only, NO atomics, no math.
// ---------------------------------------------------------------------------
__global__ __launch_bounds__(256) void k_fill(
    const int* __restrict__ ei, const int* __restrict__ offl,
    const int* __restrict__ boff, const int* __restrict__ e_slot,
    int* __restrict__ csr)
{
    int e = blockIdx.x * blockDim.x + threadIdx.x;
    if (e >= N_EDGES) return;
    int tnode = ei[e];
    int snode = ei[N_EDGES + e];
    csr[offl[tnode] + boff[tnode >> 8] + e_slot[e]] = snode;
}

// ---------------------------------------------------------------------------
// Kernel E: gather — one wave per target, lane = channel. bf16 feature
// (halves beyond-L2 traffic); weights inline via __expf; unroll x4.
// ---------------------------------------------------------------------------
__global__ __launch_bounds__(256) void k_gather(
    const float* __restrict__ e0, const float* __restrict__ e1,
    const __bf16* __restrict__ featb, const int* __restrict__ offl,
    const int* __restrict__ boff, const int* __restrict__ csr,
    float* __restrict__ out)
{
    int t = blockIdx.x * 4 + (threadIdx.x >> 6);
    int c = threadIdx.x & 63;
    if (t >= N_NODES) return;

    float e0t = e0[t];
    float z   = e0t + e1[t];
    float lr  = z > 0.f ? z : NEG_SLOPE * z;
    float wsf = __expf(lr);

    float acc  = wsf * (float)featb[(size_t)t * OUT_CH + c];
    float wsum = wsf;

    int e   = offl[t] + boff[t >> 8];
    int end = (t + 1 < N_NODES) ? (offl[t + 1] + boff[(t + 1) >> 8]) : N_EDGES;

    for (; e + 4 <= end; e += 4) {
        int s0 = csr[e], s1 = csr[e + 1], s2 = csr[e + 2], s3 = csr[e + 3];
        float q0 = e1[s0], q1 = e1[s1], q2 = e1[s2], q3 = e1[s3];
        float f0 = (float)featb[(size_t)s0 * OUT_CH + c];
        float f1 = (float)featb[(size_t)s1 * OUT_CH + c];
        float f2 = (float)featb[(size_t)s2 * OUT_CH + c];
        float f3 = (float)featb[(size_t)s3 * OUT_CH + c];
        float z0 = e0t + q0, z1 = e0t + q1, z2 = e0t + q2, z3 = e0t + q3;
        float w0 = __expf(z0 > 0.f ? z0 : NEG_SLOPE * z0);
        float w1 = __expf(z1 > 0.f ? z1 : NEG_SLOPE * z1);
        float w2 = __expf(z2 > 0.f ? z2 : NEG_SLOPE * z2);
        float w3 = __expf(z3 > 0.f ? z3 : NEG_SLOPE * z3);
        acc += w0 * f0 + w1 * f1 + w2 * f2 + w3 * f3;
        wsum += (w0 + w1) + (w2 + w3);
    }
    for (; e < end; ++e) {
        int s0 = csr[e];
        float q0 = e1[s0];
        float f0 = (float)featb[(size_t)s0 * OUT_CH + c];
        float z0 = e0t + q0;
        float w0 = __expf(z0 > 0.f ? z0 : NEG_SLOPE * z0);
        acc += w0 * f0;
        wsum += w0;
    }
    out[(size_t)t * OUT_CH + c] = acc / wsum;
}

// ---------------------------------------------------------------------------
extern "C" void kernel_launch(void* const* d_in, const int* in_sizes, int n_in,
                              void* d_out, int out_size, void* d_ws, size_t ws_size,
                              hipStream_t stream)
{
    const float* x    = (const float*)d_in[0];
    const int*   ei   = (const int*)d_in[1];
    const float* W    = (const float*)d_in[2];
    const float* bias = (const float*)d_in[3];
    const float* att  = (const float*)d_in[4];
    float* out = (float*)d_out;

    // workspace layout:
    // featb[N*64] bf16 | e0[N] f32 | e1[N] | csr[E] i32 |
    // deg[N] | offl[N] | bsum[196] | boff[197] | e_slot[E]
    __bf16* featb = (__bf16*)d_ws;
    float*  e0    = (float*)(featb + (size_t)N_NODES * OUT_CH);
    float*  e1    = e0 + N_NODES;
    int*    csr   = (int*)(e1 + N_NODES);
    int*    deg   = csr + N_EDGES;
    int*    offl  = deg + N_NODES;
    int*    bsum  = offl + N_NODES;
    int*    boff  = bsum + N_SCAN_BLKS;
    int*    e_slot= boff + N_SCAN_BLKS + 1;

    dim3 blk(256);

    k_gemm<<<dim3((N_NODES + 63) / 64), blk, 0, stream>>>(
        x, W, bias, att, featb, e0, e1, deg);

    k_hist<<<dim3((N_EDGES + 255) / 256), blk, 0, stream>>>(ei, deg, e_slot);

    k_scan_blk<<<dim3(N_SCAN_BLKS), dim3(SCAN_BLK), 0, stream>>>(deg, offl, bsum);
    k_scan_top<<<dim3(1), dim3(256), 0, stream>>>(bsum, boff);

    k_fill<<<dim3((N_EDGES + 255) / 256), blk, 0, stream>>>(
        ei, offl, boff, e_slot, csr);

    k_gather<<<dim3((N_NODES + 3) / 4), blk, 0, stream>>>(
        e0, e1, featb, offl, boff, csr, out);
}

// Round 8
// 194.041 us; speedup vs baseline: 2.1141x; 1.0199x over previous
//
#include <hip/hip_runtime.h>
#include <math.h>

#define N_NODES 50000
#define N_EDGES 800000
#define IN_CH 256
#define OUT_CH 64
#define NEG_SLOPE 0.2f

#define SCAN_BLK 256
#define N_SCAN_BLKS ((N_NODES + SCAN_BLK - 1) / SCAN_BLK)   // 196

typedef __bf16 bf16x4 __attribute__((ext_vector_type(4)));
typedef __bf16 bf16x8 __attribute__((ext_vector_type(8)));
typedef float  f32x4  __attribute__((ext_vector_type(4)));

// ---------------------------------------------------------------------------
// Kernel A: feature = x @ W^T + b via bf16 MFMA (inputs rounded to bf16,
// fp32 accumulate). K chunked in 4 stages of 64 (R5 structure): LDS
// A[64][72]+B[64][72] bf16 = 18.4 KB -> 8 blocks/CU, good inter-wave
// overlap of staging and MFMA (R7's full-K 66 KB single-stage dropped to
// 2 blocks/CU and regressed ~20us).
// Epilogue: bf16 feature store, e0/e1 att partials; zero-inits deg[].
// ---------------------------------------------------------------------------
__global__ __launch_bounds__(256) void k_gemm(
    const float* __restrict__ x, const float* __restrict__ W,
    const float* __restrict__ bias, const float* __restrict__ att,
    __bf16* __restrict__ featb, float* __restrict__ e0,
    float* __restrict__ e1, int* __restrict__ deg)
{
    __shared__ __bf16 A[64][72];
    __shared__ __bf16 B[64][72];

    const int t    = threadIdx.x;
    const int row0 = blockIdx.x * 64;
    const int wv   = t >> 6;          // wave 0..3
    const int li   = t & 63;
    const int lm   = li & 15;         // frag m/n index
    const int lq   = li >> 4;         // frag quad

    if (t < 64 && row0 + t < N_NODES) deg[row0 + t] = 0;

    f32x4 acc[4];
    #pragma unroll
    for (int tn = 0; tn < 4; ++tn) acc[tn] = (f32x4){0.f, 0.f, 0.f, 0.f};

    const int sr = t >> 2;            // staging row 0..63
    const int cq = t & 3;             // 16-float chunk within the 64-K slab
    const int gr = row0 + sr;
    const bool ok = (gr < N_NODES);

    for (int kc = 0; kc < IN_CH; kc += 64) {
        __syncthreads();              // previous chunk's MFMA reads done
        #pragma unroll
        for (int i = 0; i < 4; ++i) {
            int kk = cq * 16 + i * 4;
            float4 v = make_float4(0.f, 0.f, 0.f, 0.f);
            if (ok)
                v = *reinterpret_cast<const float4*>(&x[(size_t)gr * IN_CH + kc + kk]);
            bf16x4 h = {(__bf16)v.x, (__bf16)v.y, (__bf16)v.z, (__bf16)v.w};
            *reinterpret_cast<bf16x4*>(&A[sr][kk]) = h;

            float4 w1 = *reinterpret_cast<const float4*>(&W[(size_t)sr * IN_CH + kc + kk]);
            bf16x4 g = {(__bf16)w1.x, (__bf16)w1.y, (__bf16)w1.z, (__bf16)w1.w};
            *reinterpret_cast<bf16x4*>(&B[sr][kk]) = g;
        }
        __syncthreads();

        #pragma unroll
        for (int half = 0; half < 2; ++half) {
            int ko = half * 32 + lq * 8;
            bf16x8 a = *reinterpret_cast<const bf16x8*>(&A[wv * 16 + lm][ko]);
            #pragma unroll
            for (int tn = 0; tn < 4; ++tn) {
                bf16x8 b = *reinterpret_cast<const bf16x8*>(&B[tn * 16 + lm][ko]);
                acc[tn] = __builtin_amdgcn_mfma_f32_16x16x32_bf16(a, b, acc[tn], 0, 0, 0);
            }
        }
    }

    // ---- epilogue ----
    float att0[4], att1[4], bv[4];
    #pragma unroll
    for (int tn = 0; tn < 4; ++tn) {
        int c = tn * 16 + lm;
        att0[tn] = att[c * 2 + 0];
        att1[tn] = att[c * 2 + 1];
        bv[tn]   = bias[c];
    }

    float p0[4] = {0.f, 0.f, 0.f, 0.f};
    float p1[4] = {0.f, 0.f, 0.f, 0.f};
    #pragma unroll
    for (int r = 0; r < 4; ++r) {
        int row = row0 + wv * 16 + lq * 4 + r;   // D: row = quad*4+reg
        #pragma unroll
        for (int tn = 0; tn < 4; ++tn) {
            float f = acc[tn][r] + bv[tn];
            if (row < N_NODES)
                featb[(size_t)row * OUT_CH + tn * 16 + lm] = (__bf16)f;  // col = lane&15
            p0[r] += f * att0[tn];
            p1[r] += f * att1[tn];
        }
    }

    #pragma unroll
    for (int m = 1; m < 16; m <<= 1) {
        #pragma unroll
        for (int r = 0; r < 4; ++r) {
            p0[r] += __shfl_xor(p0[r], m, 64);
            p1[r] += __shfl_xor(p1[r], m, 64);
        }
    }
    if (lm == 0) {
        #pragma unroll
        for (int r = 0; r < 4; ++r) {
            int row = row0 + wv * 16 + lq * 4 + r;
            if (row < N_NODES) {
                e0[row] = p0[r];
                e1[row] = p1[r];
            }
        }
    }
}

// ---------------------------------------------------------------------------
// Kernel B: histogram + local slot assignment (the only per-edge atomic).
// ---------------------------------------------------------------------------
__global__ __launch_bounds__(256) void k_hist(
    const int* __restrict__ ei, int* __restrict__ deg, int* __restrict__ e_slot)
{
    int e = blockIdx.x * blockDim.x + threadIdx.x;
    if (e >= N_EDGES) return;
    e_slot[e] = atomicAdd(&deg[ei[e]], 1);
}

// ---------------------------------------------------------------------------
// Scan pass 1: per-block exclusive scan of deg -> offl, block total -> bsum
// ---------------------------------------------------------------------------
__global__ __launch_bounds__(SCAN_BLK) void k_scan_blk(
    const int* __restrict__ deg, int* __restrict__ offl, int* __restrict__ bsum)
{
    __shared__ int s[SCAN_BLK];
    int tid = threadIdx.x;
    int i = blockIdx.x * SCAN_BLK + tid;
    int v = (i < N_NODES) ? deg[i] : 0;
    s[tid] = v;
    __syncthreads();
    #pragma unroll
    for (int d = 1; d < SCAN_BLK; d <<= 1) {
        int u = (tid >= d) ? s[tid - d] : 0;
        __syncthreads();
        s[tid] += u;
        __syncthreads();
    }
    if (i < N_NODES) offl[i] = s[tid] - v;
    if (tid == SCAN_BLK - 1) bsum[blockIdx.x] = s[tid];
}

// ---------------------------------------------------------------------------
// Scan pass 2: single block scans block sums -> boff (exclusive) + sentinel
// ---------------------------------------------------------------------------
__global__ __launch_bounds__(256) void k_scan_top(
    const int* __restrict__ bsum, int* __restrict__ boff)
{
    __shared__ int s[256];
    int tid = threadIdx.x;
    int v = (tid < N_SCAN_BLKS) ? bsum[tid] : 0;
    s[tid] = v;
    __syncthreads();
    #pragma unroll
    for (int d = 1; d < 256; d <<= 1) {
        int u = (tid >= d) ? s[tid - d] : 0;
        __syncthreads();
        s[tid] += u;
        __syncthreads();
    }
    if (tid < N_SCAN_BLKS) boff[tid] = s[tid] - v;
    if (tid == 0) boff[N_SCAN_BLKS] = N_EDGES;
}

// ---------------------------------------------------------------------------
// Kernel D: CSR fill — src index only, NO atomics, no math.
// ---------------------------------------------------------------------------
__global__ __launch_bounds__(256) void k_fill(
    const int* __restrict__ ei, const int* __restrict__ offl,
    const int* __restrict__ boff, const int* __restrict__ e_slot,
    int* __restrict__ csr)
{
    int e = blockIdx.x * blockDim.x + threadIdx.x;
    if (e >= N_EDGES) return;
    int tnode = ei[e];
    int snode = ei[N_EDGES + e];
    csr[offl[tnode] + boff[tnode >> 8] + e_slot[e]] = snode;
}

// ---------------------------------------------------------------------------
// Kernel E: gather — one wave per target, lane = channel. bf16 feature
// (halves beyond-L2 traffic); weights inline via __expf; unroll x4.
// ---------------------------------------------------------------------------
__global__ __launch_bounds__(256) void k_gather(
    const float* __restrict__ e0, const float* __restrict__ e1,
    const __bf16* __restrict__ featb, const int* __restrict__ offl,
    const int* __restrict__ boff, const int* __restrict__ csr,
    float* __restrict__ out)
{
    int t = blockIdx.x * 4 + (threadIdx.x >> 6);
    int c = threadIdx.x & 63;
    if (t >= N_NODES) return;

    float e0t = e0[t];
    float z   = e0t + e1[t];
    float lr  = z > 0.f ? z : NEG_SLOPE * z;
    float wsf = __expf(lr);

    float acc  = wsf * (float)featb[(size_t)t * OUT_CH + c];
    float wsum = wsf;

    int e   = offl[t] + boff[t >> 8];
    int end = (t + 1 < N_NODES) ? (offl[t + 1] + boff[(t + 1) >> 8]) : N_EDGES;

    for (; e + 4 <= end; e += 4) {
        int s0 = csr[e], s1 = csr[e + 1], s2 = csr[e + 2], s3 = csr[e + 3];
        float q0 = e1[s0], q1 = e1[s1], q2 = e1[s2], q3 = e1[s3];
        float f0 = (float)featb[(size_t)s0 * OUT_CH + c];
        float f1 = (float)featb[(size_t)s1 * OUT_CH + c];
        float f2 = (float)featb[(size_t)s2 * OUT_CH + c];
        float f3 = (float)featb[(size_t)s3 * OUT_CH + c];
        float z0 = e0t + q0, z1 = e0t + q1, z2 = e0t + q2, z3 = e0t + q3;
        float w0 = __expf(z0 > 0.f ? z0 : NEG_SLOPE * z0);
        float w1 = __expf(z1 > 0.f ? z1 : NEG_SLOPE * z1);
        float w2 = __expf(z2 > 0.f ? z2 : NEG_SLOPE * z2);
        float w3 = __expf(z3 > 0.f ? z3 : NEG_SLOPE * z3);
        acc += w0 * f0 + w1 * f1 + w2 * f2 + w3 * f3;
        wsum += (w0 + w1) + (w2 + w3);
    }
    for (; e < end; ++e) {
        int s0 = csr[e];
        float q0 = e1[s0];
        float f0 = (float)featb[(size_t)s0 * OUT_CH + c];
        float z0 = e0t + q0;
        float w0 = __expf(z0 > 0.f ? z0 : NEG_SLOPE * z0);
        acc += w0 * f0;
        wsum += w0;
    }
    out[(size_t)t * OUT_CH + c] = acc / wsum;
}

// ---------------------------------------------------------------------------
extern "C" void kernel_launch(void* const* d_in, const int* in_sizes, int n_in,
                              void* d_out, int out_size, void* d_ws, size_t ws_size,
                              hipStream_t stream)
{
    const float* x    = (const float*)d_in[0];
    const int*   ei   = (const int*)d_in[1];
    const float* W    = (const float*)d_in[2];
    const float* bias = (const float*)d_in[3];
    const float* att  = (const float*)d_in[4];
    float* out = (float*)d_out;

    // workspace layout:
    // featb[N*64] bf16 | e0[N] f32 | e1[N] | csr[E] i32 |
    // deg[N] | offl[N] | bsum[196] | boff[197] | e_slot[E]
    __bf16* featb = (__bf16*)d_ws;
    float*  e0    = (float*)(featb + (size_t)N_NODES * OUT_CH);
    float*  e1    = e0 + N_NODES;
    int*    csr   = (int*)(e1 + N_NODES);
    int*    deg   = csr + N_EDGES;
    int*    offl  = deg + N_NODES;
    int*    bsum  = offl + N_NODES;
    int*    boff  = bsum + N_SCAN_BLKS;
    int*    e_slot= boff + N_SCAN_BLKS + 1;

    dim3 blk(256);

    k_gemm<<<dim3((N_NODES + 63) / 64), blk, 0, stream>>>(
        x, W, bias, att, featb, e0, e1, deg);

    k_hist<<<dim3((N_EDGES + 255) / 256), blk, 0, stream>>>(ei, deg, e_slot);

    k_scan_blk<<<dim3(N_SCAN_BLKS), dim3(SCAN_BLK), 0, stream>>>(deg, offl, bsum);
    k_scan_top<<<dim3(1), dim3(256), 0, stream>>>(bsum, boff);

    k_fill<<<dim3((N_EDGES + 255) / 256), blk, 0, stream>>>(
        ei, offl, boff, e_slot, csr);

    k_gather<<<dim3((N_NODES + 3) / 4), blk, 0, stream>>>(
        e0, e1, featb, offl, boff, csr, out);
}